// Round 5
// baseline (454.090 us; speedup 1.0000x reference)
//
#include <hip/hip_runtime.h>

using u16 = unsigned short;
using u32 = unsigned int;

static inline int cdiv(long long a, long long b) { return (int)((a + b - 1) / b); }

__device__ __forceinline__ u16 f2bf(float x) {
    u32 u = __builtin_bit_cast(u32, x);
    u += 0x7fffu + ((u >> 16) & 1u);   // RTNE
    return (u16)(u >> 16);
}
__device__ __forceinline__ float bflo(u32 v) {
    return __builtin_bit_cast(float, v << 16);
}
__device__ __forceinline__ float bfhi(u32 v) {
    return __builtin_bit_cast(float, v & 0xffff0000u);
}

// ---------------------------------------------------------------------------
__global__ __launch_bounds__(256) void k_hist(const int* __restrict__ ei,
                                              int* __restrict__ cnt, int E) {
    int e = blockIdx.x * 256 + threadIdx.x;
    if (e < E) atomicAdd(&cnt[ei[E + e]], 1);
}

// Per-block sums of cnt -> partial[b]
__global__ __launch_bounds__(256) void k_scan1(const int* __restrict__ cnt,
                                               int* __restrict__ partial, int N) {
    __shared__ int s[256];
    int i = blockIdx.x * 256 + threadIdx.x;
    s[threadIdx.x] = (i < N) ? cnt[i] : 0;
    __syncthreads();
    for (int st = 128; st > 0; st >>= 1) {
        if (threadIdx.x < st) s[threadIdx.x] += s[threadIdx.x + st];
        __syncthreads();
    }
    if (threadIdx.x == 0) partial[blockIdx.x] = s[0];
}

// Fused: indptr/cursor (counting-sort scan), dis = rsqrt(deg+1),
// hws1 = bf16(dis * x@Wconv0), out = b_cls + relu(x@Wego+b_ego)@Wcls0.
__global__ __launch_bounds__(256) void k_scan_input(const int* __restrict__ cnt,
                                                    const int* __restrict__ partial,
                                                    int* __restrict__ indptr,
                                                    int* __restrict__ cursor,
                                                    float* __restrict__ dis,
                                                    const float* __restrict__ x,
                                                    const float* __restrict__ Wego,
                                                    const float* __restrict__ bego,
                                                    const float* __restrict__ Wconv0,
                                                    const float* __restrict__ Wcls0,
                                                    const float* __restrict__ bcls,
                                                    u16* __restrict__ hws,
                                                    float* __restrict__ out, int N) {
    __shared__ int s[256];
    __shared__ int s_off;
    __shared__ float sWe[64 * 64];
    __shared__ float sWc[64 * 64];
    __shared__ float sWcls[64 * 40];
    __shared__ float sbe[64];
    __shared__ float sbc[40];
    for (int t = threadIdx.x; t < 64 * 64; t += 256) { sWe[t] = Wego[t]; sWc[t] = Wconv0[t]; }
    for (int t = threadIdx.x; t < 64 * 40; t += 256) sWcls[t] = Wcls0[t];
    if (threadIdx.x < 64) sbe[threadIdx.x] = bego[threadIdx.x];
    if (threadIdx.x < 40) sbc[threadIdx.x] = bcls[threadIdx.x];

    // ---- prefix of partial[0..blockIdx) ----
    int ap = 0;
    for (int j = threadIdx.x; j < blockIdx.x; j += 256) ap += partial[j];
    s[threadIdx.x] = ap;
    __syncthreads();
    for (int st = 128; st > 0; st >>= 1) {
        if (threadIdx.x < st) s[threadIdx.x] += s[threadIdx.x + st];
        __syncthreads();
    }
    if (threadIdx.x == 0) s_off = s[0];
    __syncthreads();
    const int block_off = s_off;
    __syncthreads();

    // ---- in-block inclusive scan of cnt ----
    const int i = blockIdx.x * 256 + threadIdx.x;
    const bool alive = (i < N);
    int v = alive ? cnt[i] : 0;
    s[threadIdx.x] = v;
    __syncthreads();
    for (int st = 1; st < 256; st <<= 1) {
        int add = (threadIdx.x >= st) ? s[threadIdx.x - st] : 0;
        __syncthreads();
        s[threadIdx.x] += add;
        __syncthreads();
    }
    const float dsi = rsqrtf((float)v + 1.0f);   // self-loop adds 1
    if (alive) {
        int excl = block_off + s[threadIdx.x] - v;
        indptr[i] = excl;
        cursor[i] = excl;
        dis[i] = dsi;
        if (i == N - 1) indptr[N] = excl + v;    // == E
    }

    // ---- input-layer body ----
    float xr[64];
    if (alive) {
        const float4* xp = (const float4*)(x + (size_t)i * 64);
#pragma unroll
        for (int d4 = 0; d4 < 16; ++d4) {
            float4 vv = xp[d4];
            xr[d4 * 4 + 0] = vv.x; xr[d4 * 4 + 1] = vv.y;
            xr[d4 * 4 + 2] = vv.z; xr[d4 * 4 + 3] = vv.w;
        }
    } else {
#pragma unroll
        for (int d = 0; d < 64; ++d) xr[d] = 0.f;
    }

    u32* hwp = (u32*)(hws + (size_t)i * 64);     // 64 bf16 = 32 u32 per row
    for (int c4 = 0; c4 < 16; ++c4) {
        float4 acc = {0.f, 0.f, 0.f, 0.f};
#pragma unroll
        for (int d = 0; d < 64; ++d) {
            float xd = xr[d];
            const float4 w = *(const float4*)&sWc[d * 64 + c4 * 4];
            acc.x += xd * w.x; acc.y += xd * w.y;
            acc.z += xd * w.z; acc.w += xd * w.w;
        }
        if (alive) {
            hwp[c4 * 2 + 0] = (u32)f2bf(dsi * acc.x) | ((u32)f2bf(dsi * acc.y) << 16);
            hwp[c4 * 2 + 1] = (u32)f2bf(dsi * acc.z) | ((u32)f2bf(dsi * acc.w) << 16);
        }
    }

    float oacc[40];
#pragma unroll
    for (int j = 0; j < 40; ++j) oacc[j] = sbc[j];
    for (int c = 0; c < 64; ++c) {
        float acc = sbe[c];
#pragma unroll
        for (int d = 0; d < 64; ++d) acc += xr[d] * sWe[d * 64 + c];
        acc = fmaxf(acc, 0.0f);
#pragma unroll
        for (int j = 0; j < 40; ++j) oacc[j] += acc * sWcls[c * 40 + j];
    }
    if (alive) {
        float* op = out + (size_t)i * 40;
#pragma unroll
        for (int j = 0; j < 40; ++j) op[j] = oacc[j];
    }
}

// Fill CSR rows via atomic cursors (order within a segment is arbitrary).
__global__ __launch_bounds__(256) void k_reorder(const int* __restrict__ ei,
                                                 int* __restrict__ cursor,
                                                 int* __restrict__ rows, int E) {
    int e = blockIdx.x * 256 + threadIdx.x;
    if (e < E) {
        int r = ei[e];
        int c = ei[E + e];
        int pos = atomicAdd(&cursor[c], 1);
        rows[pos] = r;
    }
}

// ---------------------------------------------------------------------------
// Fused hop v3: block = 256 thr = 4 waves; 8 nodes per wave (32/block).
// Gather: lane handles a bf16 feature-PAIR (u32); half-waves take even/odd
// edges; combine via shfl_xor(32). h -> LDS sh[wave][8][64] (fp32).
// MLP: W columns hoisted to VGPRs from global (L2-hot), sh read as broadcast
// b128 -> no per-node W traffic through LDS.
template <bool LAST>
__global__ __launch_bounds__(256, 3) void k_hop(const int* __restrict__ indptr,
                                                const int* __restrict__ rows,
                                                const float* __restrict__ dis,
                                                const float* __restrict__ bconv,
                                                const float* __restrict__ Wnext,
                                                const float* __restrict__ WclsPart,
                                                const u16* __restrict__ hws_in,
                                                u16* __restrict__ hws_out,
                                                float* __restrict__ out, int N) {
    __shared__ float sh[4][8][64];
    const int wv = threadIdx.x >> 6;
    const int l  = threadIdx.x & 63;
    const int q  = l >> 5;          // half-wave parity (even/odd edges)
    const int c  = l & 31;          // feature pair base: features 2c, 2c+1
    const int node0 = blockIdx.x * 32 + wv * 8;
    if (node0 >= N) return;

    // preload indptr / dis for this wave's 8 nodes (lane-indexed, then shfl)
    int ipl = indptr[node0 + (l <= 8 ? l : 8) <= N ? node0 + (l <= 8 ? l : 8) : N];
    float dl = dis[(node0 + (l < 8 ? l : 7)) < N ? (node0 + (l < 8 ? l : 7)) : (N - 1)];

    const float2 bb = *(const float2*)(bconv + 2 * c);

    // ---- gather phase: 8 nodes serially ----
    for (int n = 0; n < 8; ++n) {
        const int i = node0 + n;
        if (i >= N) break;
        int p0 = __shfl(ipl, n, 64);
        int p1 = __shfl(ipl, n + 1, 64);
        float a0 = 0.f, a1 = 0.f;
        int p = p0 + q;
        for (; p + 6 < p1; p += 8) {    // 4 edge-pairs per half-wave in flight
            int r0 = rows[p + 0], r1 = rows[p + 2], r2 = rows[p + 4], r3 = rows[p + 6];
            u32 v0 = *(const u32*)(hws_in + (size_t)r0 * 64 + 2 * c);
            u32 v1 = *(const u32*)(hws_in + (size_t)r1 * 64 + 2 * c);
            u32 v2 = *(const u32*)(hws_in + (size_t)r2 * 64 + 2 * c);
            u32 v3 = *(const u32*)(hws_in + (size_t)r3 * 64 + 2 * c);
            a0 += (bflo(v0) + bflo(v1)) + (bflo(v2) + bflo(v3));
            a1 += (bfhi(v0) + bfhi(v1)) + (bfhi(v2) + bfhi(v3));
        }
        for (; p < p1; p += 2) {
            u32 v = *(const u32*)(hws_in + (size_t)rows[p] * 64 + 2 * c);
            a0 += bflo(v);
            a1 += bfhi(v);
        }
        a0 += __shfl_xor(a0, 32, 64);   // combine even/odd halves
        a1 += __shfl_xor(a1, 32, 64);
        u32 sv = *(const u32*)(hws_in + (size_t)i * 64 + 2 * c);  // self-loop
        float dsi = __shfl(dl, n, 64);
        float h0 = fmaxf(fmaf(dsi, a0 + bflo(sv), bb.x), 0.f);
        float h1 = fmaxf(fmaf(dsi, a1 + bfhi(sv), bb.y), 0.f);
        if (q == 0) *(float2*)&sh[wv][n][2 * c] = make_float2(h0, h1);
    }
    __syncthreads();   // one barrier; sh tiles now complete

    const int f = l;   // output column for this thread
    if (!LAST) {
        float wn[64];
#pragma unroll
        for (int d = 0; d < 64; ++d) wn[d] = Wnext[d * 64 + f];  // coalesced, L2-hot
        for (int n = 0; n < 8; ++n) {
            const int i = node0 + n;
            if (i >= N) break;
            float acc = 0.f;
#pragma unroll
            for (int d4 = 0; d4 < 16; ++d4) {
                float4 s4 = *(const float4*)&sh[wv][n][d4 * 4];  // broadcast read
                acc = fmaf(s4.x, wn[d4 * 4 + 0], acc);
                acc = fmaf(s4.y, wn[d4 * 4 + 1], acc);
                acc = fmaf(s4.z, wn[d4 * 4 + 2], acc);
                acc = fmaf(s4.w, wn[d4 * 4 + 3], acc);
            }
            hws_out[(size_t)i * 64 + f] = f2bf(__shfl(dl, n, 64) * acc);
        }
    }
    {
        float wc[64];
#pragma unroll
        for (int d = 0; d < 64; ++d) wc[d] = (f < 40) ? WclsPart[d * 40 + f] : 0.f;
        for (int n = 0; n < 8; ++n) {
            const int i = node0 + n;
            if (i >= N) break;
            float acc = 0.f;
#pragma unroll
            for (int d4 = 0; d4 < 16; ++d4) {
                float4 s4 = *(const float4*)&sh[wv][n][d4 * 4];
                acc = fmaf(s4.x, wc[d4 * 4 + 0], acc);
                acc = fmaf(s4.y, wc[d4 * 4 + 1], acc);
                acc = fmaf(s4.z, wc[d4 * 4 + 2], acc);
                acc = fmaf(s4.w, wc[d4 * 4 + 3], acc);
            }
            if (f < 40) out[(size_t)i * 40 + f] += acc;
        }
    }
}

// ---------------------------------------------------------------------------
extern "C" void kernel_launch(void* const* d_in, const int* in_sizes, int n_in,
                              void* d_out, int out_size, void* d_ws, size_t ws_size,
                              hipStream_t stream) {
    const float* x     = (const float*)d_in[0];
    const int*   ei    = (const int*)d_in[1];   // [2,E] int32
    const float* Wego  = (const float*)d_in[2];
    const float* bego  = (const float*)d_in[3];
    const float* Wconv = (const float*)d_in[4]; // [2,64,64]
    const float* bconv = (const float*)d_in[5]; // [2,64]
    const float* Wcls  = (const float*)d_in[6]; // [192,40]
    const float* bcls  = (const float*)d_in[7];
    float* out = (float*)d_out;

    const int N = in_sizes[0] / 64;
    const int E = in_sizes[1] / 2;
    const int nb = cdiv(N, 256);

    // workspace layout:
    //  hws1 u16[N*64] | hws2 u16[N*64] | dis f[N] | cnt i[N] | indptr i[N+1] |
    //  cursor i[N] | partial i[512] | rows i[E]
    u16* hws1 = (u16*)d_ws;
    u16* hws2 = hws1 + (size_t)N * 64;
    float* dis = (float*)(hws2 + (size_t)N * 64);
    int* cnt     = (int*)(dis + N);
    int* indptr  = cnt + N;
    int* cursor  = indptr + (N + 1);
    int* partial = cursor + N;
    int* rows    = partial + 512;

    hipMemsetAsync(cnt, 0, sizeof(int) * (size_t)N, stream);

    // ---- CSR build + fused input ----
    k_hist<<<cdiv(E, 256), 256, 0, stream>>>(ei, cnt, E);
    k_scan1<<<nb, 256, 0, stream>>>(cnt, partial, N);
    k_scan_input<<<nb, 256, 0, stream>>>(cnt, partial, indptr, cursor, dis,
                                         x, Wego, bego, Wconv, Wcls, bcls,
                                         hws1, out, N);
    k_reorder<<<cdiv(E, 256), 256, 0, stream>>>(ei, cursor, rows, E);

    // ---- hop 1 ----
    k_hop<false><<<cdiv(N, 32), 256, 0, stream>>>(indptr, rows, dis, bconv,
                                                  Wconv + 64 * 64, Wcls + 64 * 40,
                                                  hws1, hws2, out, N);
    // ---- hop 2 ----
    k_hop<true><<<cdiv(N, 32), 256, 0, stream>>>(indptr, rows, dis, bconv + 64,
                                                 Wconv, Wcls + 2 * 64 * 40,
                                                 hws2, nullptr, out, N);
}

// Round 6
// 341.333 us; speedup vs baseline: 1.3303x; 1.3303x over previous
//
#include <hip/hip_runtime.h>

using u16 = unsigned short;
using u32 = unsigned int;
using short8 = __attribute__((ext_vector_type(8))) short;
using f32x4  = __attribute__((ext_vector_type(4))) float;

static inline int cdiv(long long a, long long b) { return (int)((a + b - 1) / b); }

__device__ __forceinline__ u16 f2bf(float x) {
    u32 u = __builtin_bit_cast(u32, x);
    u += 0x7fffu + ((u >> 16) & 1u);   // RTNE
    return (u16)(u >> 16);
}
__device__ __forceinline__ float bf2f(u16 h) {
    u32 u = ((u32)h) << 16;
    return __builtin_bit_cast(float, u);
}

// ---------------------------------------------------------------------------
__global__ __launch_bounds__(256) void k_hist(const int* __restrict__ ei,
                                              int* __restrict__ cnt, int E) {
    int e = blockIdx.x * 256 + threadIdx.x;
    if (e < E) atomicAdd(&cnt[ei[E + e]], 1);
}

__global__ __launch_bounds__(256) void k_scan1(const int* __restrict__ cnt,
                                               int* __restrict__ partial, int N) {
    __shared__ int s[256];
    int i = blockIdx.x * 256 + threadIdx.x;
    s[threadIdx.x] = (i < N) ? cnt[i] : 0;
    __syncthreads();
    for (int st = 128; st > 0; st >>= 1) {
        if (threadIdx.x < st) s[threadIdx.x] += s[threadIdx.x + st];
        __syncthreads();
    }
    if (threadIdx.x == 0) partial[blockIdx.x] = s[0];
}

// Fused: indptr/cursor (counting-sort scan), dis = rsqrt(deg+1),
// hws1 = bf16(dis * x@Wconv0), out = b_cls + relu(x@Wego+b_ego)@Wcls0.
__global__ __launch_bounds__(256) void k_scan_input(const int* __restrict__ cnt,
                                                    const int* __restrict__ partial,
                                                    int* __restrict__ indptr,
                                                    int* __restrict__ cursor,
                                                    float* __restrict__ dis,
                                                    const float* __restrict__ x,
                                                    const float* __restrict__ Wego,
                                                    const float* __restrict__ bego,
                                                    const float* __restrict__ Wconv0,
                                                    const float* __restrict__ Wcls0,
                                                    const float* __restrict__ bcls,
                                                    u16* __restrict__ hws,
                                                    float* __restrict__ out, int N) {
    __shared__ int s[256];
    __shared__ int s_off;
    __shared__ float sWe[64 * 64];
    __shared__ float sWc[64 * 64];
    __shared__ float sWcls[64 * 40];
    __shared__ float sbe[64];
    __shared__ float sbc[40];
    for (int t = threadIdx.x; t < 64 * 64; t += 256) { sWe[t] = Wego[t]; sWc[t] = Wconv0[t]; }
    for (int t = threadIdx.x; t < 64 * 40; t += 256) sWcls[t] = Wcls0[t];
    if (threadIdx.x < 64) sbe[threadIdx.x] = bego[threadIdx.x];
    if (threadIdx.x < 40) sbc[threadIdx.x] = bcls[threadIdx.x];

    // ---- prefix of partial[0..blockIdx) ----
    int ap = 0;
    for (int j = threadIdx.x; j < blockIdx.x; j += 256) ap += partial[j];
    s[threadIdx.x] = ap;
    __syncthreads();
    for (int st = 128; st > 0; st >>= 1) {
        if (threadIdx.x < st) s[threadIdx.x] += s[threadIdx.x + st];
        __syncthreads();
    }
    if (threadIdx.x == 0) s_off = s[0];
    __syncthreads();
    const int block_off = s_off;
    __syncthreads();

    // ---- in-block inclusive scan of cnt ----
    const int i = blockIdx.x * 256 + threadIdx.x;
    const bool alive = (i < N);
    int v = alive ? cnt[i] : 0;
    s[threadIdx.x] = v;
    __syncthreads();
    for (int st = 1; st < 256; st <<= 1) {
        int add = (threadIdx.x >= st) ? s[threadIdx.x - st] : 0;
        __syncthreads();
        s[threadIdx.x] += add;
        __syncthreads();
    }
    const float dsi = rsqrtf((float)v + 1.0f);   // self-loop adds 1
    if (alive) {
        int excl = block_off + s[threadIdx.x] - v;
        indptr[i] = excl;
        cursor[i] = excl;
        dis[i] = dsi;
        if (i == N - 1) indptr[N] = excl + v;    // == E
    }

    // ---- input-layer body ----
    float xr[64];
    if (alive) {
        const float4* xp = (const float4*)(x + (size_t)i * 64);
#pragma unroll
        for (int d4 = 0; d4 < 16; ++d4) {
            float4 vv = xp[d4];
            xr[d4 * 4 + 0] = vv.x; xr[d4 * 4 + 1] = vv.y;
            xr[d4 * 4 + 2] = vv.z; xr[d4 * 4 + 3] = vv.w;
        }
    } else {
#pragma unroll
        for (int d = 0; d < 64; ++d) xr[d] = 0.f;
    }

    u32* hwp = (u32*)(hws + (size_t)i * 64);     // 64 bf16 = 32 u32 per row
    for (int c4 = 0; c4 < 16; ++c4) {
        float4 acc = {0.f, 0.f, 0.f, 0.f};
#pragma unroll
        for (int d = 0; d < 64; ++d) {
            float xd = xr[d];
            const float4 w = *(const float4*)&sWc[d * 64 + c4 * 4];
            acc.x += xd * w.x; acc.y += xd * w.y;
            acc.z += xd * w.z; acc.w += xd * w.w;
        }
        if (alive) {
            hwp[c4 * 2 + 0] = (u32)f2bf(dsi * acc.x) | ((u32)f2bf(dsi * acc.y) << 16);
            hwp[c4 * 2 + 1] = (u32)f2bf(dsi * acc.z) | ((u32)f2bf(dsi * acc.w) << 16);
        }
    }

    float oacc[40];
#pragma unroll
    for (int j = 0; j < 40; ++j) oacc[j] = sbc[j];
    for (int c = 0; c < 64; ++c) {
        float acc = sbe[c];
#pragma unroll
        for (int d = 0; d < 64; ++d) acc += xr[d] * sWe[d * 64 + c];
        acc = fmaxf(acc, 0.0f);
#pragma unroll
        for (int j = 0; j < 40; ++j) oacc[j] += acc * sWcls[c * 40 + j];
    }
    if (alive) {
        float* op = out + (size_t)i * 40;
#pragma unroll
        for (int j = 0; j < 40; ++j) op[j] = oacc[j];
    }
}

// Fill CSR rows via atomic cursors (order within a segment is arbitrary).
__global__ __launch_bounds__(256) void k_reorder(const int* __restrict__ ei,
                                                 int* __restrict__ cursor,
                                                 int* __restrict__ rows, int E) {
    int e = blockIdx.x * 256 + threadIdx.x;
    if (e < E) {
        int r = ei[e];
        int c = ei[E + e];
        int pos = atomicAdd(&cursor[c], 1);
        rows[pos] = r;
    }
}

// Transposed bf16 weight panels for the MFMA MLPs.
// WT1 [112][64]: rows 0..63 = Wconv[1] cols; rows 64..103 = Wcls[64:128] cols; pad 0.
// WT2 [48][64]:  rows 0..39 = Wcls[128:192] cols; pad 0.
__global__ __launch_bounds__(256) void k_prep(const float* __restrict__ Wconv,
                                              const float* __restrict__ Wcls,
                                              u16* __restrict__ WT1,
                                              u16* __restrict__ WT2) {
    int t = blockIdx.x * 256 + threadIdx.x;
    if (t < 112 * 64) {
        int c = t >> 6, d = t & 63;
        float v = 0.f;
        if (c < 64) v = Wconv[64 * 64 + d * 64 + c];
        else if (c < 104) v = Wcls[(64 + d) * 40 + (c - 64)];
        WT1[t] = f2bf(v);
    } else if (t < 112 * 64 + 48 * 64) {
        int u = t - 112 * 64;
        int c = u >> 6, d = u & 63;
        float v = (c < 40) ? Wcls[(128 + d) * 40 + c] : 0.f;
        WT2[u] = f2bf(v);
    }
}

// ---------------------------------------------------------------------------
// Pure gather (R4 structure): one wave per node, lane f = feature.
// h[i][f] = relu(dis[i] * (self + sum_nbr) + bconv[f]), stored bf16.
__global__ __launch_bounds__(512) void k_gather(const int* __restrict__ indptr,
                                                const int* __restrict__ rows,
                                                const float* __restrict__ dis,
                                                const float* __restrict__ bconv,
                                                const u16* __restrict__ hws_in,
                                                u16* __restrict__ h, int N) {
    const int w = threadIdx.x >> 6;
    const int f = threadIdx.x & 63;
    const int i = blockIdx.x * 8 + w;
    if (i >= N) return;

    float acc = bf2f(hws_in[(size_t)i * 64 + f]);   // self-loop term
    int p0 = __builtin_amdgcn_readfirstlane(indptr[i]);
    int p1 = __builtin_amdgcn_readfirstlane(indptr[i + 1]);
    int p = p0;
    for (; p + 8 <= p1; p += 8) {
        int r0 = rows[p + 0], r1 = rows[p + 1], r2 = rows[p + 2], r3 = rows[p + 3];
        int r4 = rows[p + 4], r5 = rows[p + 5], r6 = rows[p + 6], r7 = rows[p + 7];
        u16 v0 = hws_in[(size_t)r0 * 64 + f];
        u16 v1 = hws_in[(size_t)r1 * 64 + f];
        u16 v2 = hws_in[(size_t)r2 * 64 + f];
        u16 v3 = hws_in[(size_t)r3 * 64 + f];
        u16 v4 = hws_in[(size_t)r4 * 64 + f];
        u16 v5 = hws_in[(size_t)r5 * 64 + f];
        u16 v6 = hws_in[(size_t)r6 * 64 + f];
        u16 v7 = hws_in[(size_t)r7 * 64 + f];
        acc += ((bf2f(v0) + bf2f(v1)) + (bf2f(v2) + bf2f(v3))) +
               ((bf2f(v4) + bf2f(v5)) + (bf2f(v6) + bf2f(v7)));
    }
    for (; p + 4 <= p1; p += 4) {
        int r0 = rows[p + 0], r1 = rows[p + 1], r2 = rows[p + 2], r3 = rows[p + 3];
        u16 v0 = hws_in[(size_t)r0 * 64 + f];
        u16 v1 = hws_in[(size_t)r1 * 64 + f];
        u16 v2 = hws_in[(size_t)r2 * 64 + f];
        u16 v3 = hws_in[(size_t)r3 * 64 + f];
        acc += (bf2f(v0) + bf2f(v1)) + (bf2f(v2) + bf2f(v3));
    }
    for (; p < p1; ++p) acc += bf2f(hws_in[(size_t)rows[p] * 64 + f]);

    float hv = fmaxf(fmaf(dis[i], acc, bconv[f]), 0.0f);
    h[(size_t)i * 64 + f] = f2bf(hv);
}

// ---------------------------------------------------------------------------
// MFMA MLP: D[N,104] = h[N,64] @ [Wnext | WclsPart].
// One wave per 16-row tile; A-frags loaded once, loop over NC 16-col tiles.
// Epilogue: cols <64 -> hws_out = bf16(dis*val); cols 64..103 -> out +=.
// For HAS_NEXT=false (hop 2): all cols are out cols (WT = Wcls^T only).
// mfma_f32_16x16x32_bf16 layouts: A row=l&15,k=(l>>4)*8+j; B col=l&15,same k;
// C/D col=l&15, row=(l>>4)*4+reg  [guide §3, m89/m91].
template <int NC, bool HAS_NEXT>
__global__ __launch_bounds__(256) void k_mlp(const u16* __restrict__ h,
                                             const u16* __restrict__ WT,
                                             const float* __restrict__ dis,
                                             u16* __restrict__ hws_out,
                                             float* __restrict__ out, int N) {
    const int wid = (blockIdx.x * 256 + threadIdx.x) >> 6;  // global wave = row tile
    const int l = threadIdx.x & 63;
    if (wid * 16 >= N) return;
    const int lr = l & 15;        // A row / B col / D col selector
    const int lk = l >> 4;        // k-block (0..3)

    const u16* hrow = h + ((size_t)(wid * 16 + lr)) * 64 + lk * 8;
    short8 a0 = *(const short8*)hrow;          // k = lk*8 .. +7   (K 0..31)
    short8 a1 = *(const short8*)(hrow + 32);   // k 32..63

    float dvals[4];
    if (HAS_NEXT) {
#pragma unroll
        for (int rg = 0; rg < 4; ++rg) dvals[rg] = dis[wid * 16 + lk * 4 + rg];
    }

    for (int ct = 0; ct < NC; ++ct) {
        const u16* wrow = WT + ((size_t)(ct * 16 + lr)) * 64 + lk * 8;
        short8 b0 = *(const short8*)wrow;
        short8 b1 = *(const short8*)(wrow + 32);
        f32x4 acc = {0.f, 0.f, 0.f, 0.f};
        acc = __builtin_amdgcn_mfma_f32_16x16x32_bf16(a0, b0, acc, 0, 0, 0);
        acc = __builtin_amdgcn_mfma_f32_16x16x32_bf16(a1, b1, acc, 0, 0, 0);
        const int col = ct * 16 + lr;
#pragma unroll
        for (int rg = 0; rg < 4; ++rg) {
            const int r = wid * 16 + lk * 4 + rg;
            if (HAS_NEXT) {
                if (col < 64) {
                    hws_out[(size_t)r * 64 + col] = f2bf(dvals[rg] * acc[rg]);
                } else {
                    int oc = col - 64;
                    if (oc < 40) out[(size_t)r * 40 + oc] += acc[rg];
                }
            } else {
                if (col < 40) out[(size_t)r * 40 + col] += acc[rg];
            }
        }
    }
}

// ---------------------------------------------------------------------------
extern "C" void kernel_launch(void* const* d_in, const int* in_sizes, int n_in,
                              void* d_out, int out_size, void* d_ws, size_t ws_size,
                              hipStream_t stream) {
    const float* x     = (const float*)d_in[0];
    const int*   ei    = (const int*)d_in[1];   // [2,E] int32
    const float* Wego  = (const float*)d_in[2];
    const float* bego  = (const float*)d_in[3];
    const float* Wconv = (const float*)d_in[4]; // [2,64,64]
    const float* bconv = (const float*)d_in[5]; // [2,64]
    const float* Wcls  = (const float*)d_in[6]; // [192,40]
    const float* bcls  = (const float*)d_in[7];
    float* out = (float*)d_out;

    const int N = in_sizes[0] / 64;
    const int E = in_sizes[1] / 2;
    const int nb = cdiv(N, 256);

    // workspace layout (u16/f32/i32, all 16B-aligned offsets):
    //  hws1 u16[N*64] | hws2 u16[N*64] | h u16[N*64] | WT1 u16[112*64] |
    //  WT2 u16[48*64] | dis f[N] | cnt i[N] | indptr i[N+1] | cursor i[N] |
    //  partial i[512] | rows i[E]
    u16* hws1 = (u16*)d_ws;
    u16* hws2 = hws1 + (size_t)N * 64;
    u16* h    = hws2 + (size_t)N * 64;
    u16* WT1  = h + (size_t)N * 64;
    u16* WT2  = WT1 + 112 * 64;
    float* dis = (float*)(WT2 + 48 * 64);
    int* cnt     = (int*)(dis + N);
    int* indptr  = cnt + N;
    int* cursor  = indptr + (N + 1);
    int* partial = cursor + N;
    int* rows    = partial + 512;

    hipMemsetAsync(cnt, 0, sizeof(int) * (size_t)N, stream);

    // ---- CSR build + fused input + weight prep ----
    k_hist<<<cdiv(E, 256), 256, 0, stream>>>(ei, cnt, E);
    k_scan1<<<nb, 256, 0, stream>>>(cnt, partial, N);
    k_scan_input<<<nb, 256, 0, stream>>>(cnt, partial, indptr, cursor, dis,
                                         x, Wego, bego, Wconv, Wcls, bcls,
                                         hws1, out, N);
    k_reorder<<<cdiv(E, 256), 256, 0, stream>>>(ei, cursor, rows, E);
    k_prep<<<cdiv((112 + 48) * 64, 256), 256, 0, stream>>>(Wconv, Wcls, WT1, WT2);

    const int n_rt = cdiv(N, 16);              // 16-row tiles (N=100000 -> 6250)
    // ---- hop 1 ----
    k_gather<<<cdiv(N, 8), 512, 0, stream>>>(indptr, rows, dis, bconv, hws1, h, N);
    k_mlp<7, true><<<cdiv(n_rt, 4), 256, 0, stream>>>(h, WT1, dis, hws2, out, N);
    // ---- hop 2 ----
    k_gather<<<cdiv(N, 8), 512, 0, stream>>>(indptr, rows, dis, bconv + 64, hws2, h, N);
    k_mlp<3, false><<<cdiv(n_rt, 4), 256, 0, stream>>>(h, WT2, dis, nullptr, out, N);
}

// Round 7
// 223.342 us; speedup vs baseline: 2.0332x; 1.5283x over previous
//
#include <hip/hip_runtime.h>

using u16 = unsigned short;
using u32 = unsigned int;
using u64 = unsigned long long;
using short8 = __attribute__((ext_vector_type(8))) short;
using f32x4  = __attribute__((ext_vector_type(4))) float;

static inline int cdiv(long long a, long long b) { return (int)((a + b - 1) / b); }

__device__ __forceinline__ u16 f2bf(float x) {
    u32 u = __builtin_bit_cast(u32, x);
    u += 0x7fffu + ((u >> 16) & 1u);   // RTNE
    return (u16)(u >> 16);
}
__device__ __forceinline__ float bf2f(u16 h) {
    u32 u = ((u32)h) << 16;
    return __builtin_bit_cast(float, u);
}

// ===========================================================================
// CSR build, 2-level counting sort. Bucket = 1024 destination nodes.
#define BKT_SH 10
#define CHUNK 4096

// Per-block LDS bucket histogram -> global bucket counts.
__global__ __launch_bounds__(256) void k_bhist(const int* __restrict__ ei,
                                               int* __restrict__ bcntg, int E) {
    __shared__ int lb[128];
    if (threadIdx.x < 128) lb[threadIdx.x] = 0;
    __syncthreads();
    const int eb = blockIdx.x * CHUNK;
#pragma unroll
    for (int k = 0; k < 16; ++k) {
        int e = eb + k * 256 + threadIdx.x;
        if (e < E) atomicAdd(&lb[ei[E + e] >> BKT_SH], 1);
    }
    __syncthreads();
    if (threadIdx.x < 128 && lb[threadIdx.x] > 0)
        atomicAdd(&bcntg[threadIdx.x], lb[threadIdx.x]);
}

// Exclusive scan of NB bucket counts (NB <= 128), single block.
__global__ __launch_bounds__(128) void k_bscan(const int* __restrict__ bcntg,
                                               int* __restrict__ bbase,
                                               int* __restrict__ bcursor, int NB) {
    __shared__ int s[128];
    int t = threadIdx.x;
    int v = (t < NB) ? bcntg[t] : 0;
    s[t] = v;
    __syncthreads();
    for (int st = 1; st < 128; st <<= 1) {
        int add = (t >= st) ? s[t - st] : 0;
        __syncthreads();
        s[t] += add;
        __syncthreads();
    }
    int excl = s[t] - v;
    if (t < NB) { bbase[t] = excl; bcursor[t] = excl; }
    if (t == NB - 1) bbase[NB] = excl + v;   // == E
}

// Bin edges into bucket-major staging (u64 = c<<32 | r), block-coalesced runs.
__global__ __launch_bounds__(256) void k_passA(const int* __restrict__ ei,
                                               int* __restrict__ bcursor,
                                               u64* __restrict__ sta, int E) {
    __shared__ int lcnt[128];
    __shared__ int lcur[128];
    if (threadIdx.x < 128) lcnt[threadIdx.x] = 0;
    __syncthreads();
    const int eb = blockIdx.x * CHUNK;
    int er[16], ec[16];
#pragma unroll
    for (int k = 0; k < 16; ++k) {
        int e = eb + k * 256 + threadIdx.x;
        if (e < E) {
            er[k] = ei[e];
            ec[k] = ei[E + e];
            atomicAdd(&lcnt[ec[k] >> BKT_SH], 1);
        } else {
            ec[k] = -1;
        }
    }
    __syncthreads();
    if (threadIdx.x < 128)
        lcur[threadIdx.x] = lcnt[threadIdx.x] > 0
                          ? atomicAdd(&bcursor[threadIdx.x], lcnt[threadIdx.x]) : 0;
    __syncthreads();
#pragma unroll
    for (int k = 0; k < 16; ++k) {
        if (ec[k] >= 0) {
            int pos = atomicAdd(&lcur[ec[k] >> BKT_SH], 1);
            sta[pos] = ((u64)(u32)ec[k] << 32) | (u32)er[k];
        }
    }
}

// One block per bucket: per-node count -> indptr/dis, then place rows[].
__global__ __launch_bounds__(256) void k_passB(const u64* __restrict__ sta,
                                               const int* __restrict__ bbase,
                                               int* __restrict__ indptr,
                                               float* __restrict__ dis,
                                               int* __restrict__ rows,
                                               int N, int NB) {
    __shared__ int lcnt[1024];
    __shared__ int cur[1024];
    __shared__ int ps[256];
    const int b = blockIdx.x;
    const int t = threadIdx.x;
    const int base = b << BKT_SH;
    const int e0 = bbase[b], e1 = bbase[b + 1];

#pragma unroll
    for (int k = 0; k < 4; ++k) lcnt[k * 256 + t] = 0;
    __syncthreads();
    for (int e = e0 + t; e < e1; e += 256)
        atomicAdd(&lcnt[(int)(sta[e] >> 32) - base], 1);
    __syncthreads();

    // exclusive scan of 1024 counts: 4 per thread + block scan of sums
    int a0 = lcnt[t * 4 + 0], a1 = lcnt[t * 4 + 1];
    int a2 = lcnt[t * 4 + 2], a3 = lcnt[t * 4 + 3];
    int sum = a0 + a1 + a2 + a3;
    ps[t] = sum;
    __syncthreads();
    for (int st = 1; st < 256; st <<= 1) {
        int add = (t >= st) ? ps[t - st] : 0;
        __syncthreads();
        ps[t] += add;
        __syncthreads();
    }
    int ex = e0 + ps[t] - sum;   // global exclusive prefix for node t*4
    int exs[4] = {ex, ex + a0, ex + a0 + a1, ex + a0 + a1 + a2};
    int cnts[4] = {a0, a1, a2, a3};
#pragma unroll
    for (int k = 0; k < 4; ++k) {
        int j = t * 4 + k;
        cur[j] = exs[k];
        int node = base + j;
        if (node < N) {
            indptr[node] = exs[k];
            dis[node] = rsqrtf((float)cnts[k] + 1.0f);   // self-loop adds 1
        }
    }
    if (b == NB - 1 && t == 0) indptr[N] = bbase[NB];    // == E
    __syncthreads();

    for (int e = e0 + t; e < e1; e += 256) {
        u64 v = sta[e];
        int c = (int)(v >> 32);
        int pos = atomicAdd(&cur[c - base], 1);
        rows[pos] = (int)(u32)v;
    }
}

// ===========================================================================
// x (fp32) -> xb (bf16), 8 elems/thread.
__global__ __launch_bounds__(256) void k_cast(const float* __restrict__ x,
                                              u32* __restrict__ xb, long long n8) {
    long long t = (long long)blockIdx.x * 256 + threadIdx.x;
    if (t >= n8) return;
    const float4* xp = (const float4*)(x + t * 8);
    float4 v0 = xp[0], v1 = xp[1];
    u32* o = xb + t * 4;
    o[0] = (u32)f2bf(v0.x) | ((u32)f2bf(v0.y) << 16);
    o[1] = (u32)f2bf(v0.z) | ((u32)f2bf(v0.w) << 16);
    o[2] = (u32)f2bf(v1.x) | ((u32)f2bf(v1.y) << 16);
    o[3] = (u32)f2bf(v1.z) | ((u32)f2bf(v1.w) << 16);
}

// Transposed bf16 weight panels.
// WTin [128][64]: rows 0..63 = Wconv[0] cols; 64..127 = Wego cols.
// WTc0 [48][64]:  rows 0..39 = Wcls[0:64] cols; pad 0.
// WT1 [112][64]:  rows 0..63 = Wconv[1] cols; 64..103 = Wcls[64:128] cols; pad 0.
// WT2 [48][64]:   rows 0..39 = Wcls[128:192] cols; pad 0.
__global__ __launch_bounds__(256) void k_prep(const float* __restrict__ Wego,
                                              const float* __restrict__ Wconv,
                                              const float* __restrict__ Wcls,
                                              u16* __restrict__ WTin,
                                              u16* __restrict__ WTc0,
                                              u16* __restrict__ WT1,
                                              u16* __restrict__ WT2) {
    int t = blockIdx.x * 256 + threadIdx.x;
    int seg = t >> 6;        // panel row
    int d = t & 63;          // k index
    if (seg < 128) {
        float v = (seg < 64) ? Wconv[d * 64 + seg] : Wego[d * 64 + (seg - 64)];
        WTin[seg * 64 + d] = f2bf(v);
    } else if (seg < 176) {
        int c = seg - 128;
        WTc0[c * 64 + d] = f2bf(c < 40 ? Wcls[d * 40 + c] : 0.f);
    } else if (seg < 288) {
        int c = seg - 176;
        float v = 0.f;
        if (c < 64) v = Wconv[64 * 64 + d * 64 + c];
        else if (c < 104) v = Wcls[(64 + d) * 40 + (c - 64)];
        WT1[c * 64 + d] = f2bf(v);
    } else if (seg < 336) {
        int c = seg - 288;
        WT2[c * 64 + d] = f2bf(c < 40 ? Wcls[(128 + d) * 40 + c] : 0.f);
    }
}

// ===========================================================================
// MFMA input layer: [N,64]@[Wconv0|Wego] -> hws1 (bf16, dis-scaled), p0 (bf16 relu).
__global__ __launch_bounds__(256) void k_in(const u16* __restrict__ xb,
                                            const u16* __restrict__ WTin,
                                            const float* __restrict__ dis,
                                            const float* __restrict__ bego,
                                            u16* __restrict__ hws1,
                                            u16* __restrict__ p0, int N) {
    const int wid = (blockIdx.x * 256 + threadIdx.x) >> 6;
    const int l = threadIdx.x & 63;
    if (wid * 16 >= N) return;
    const int lr = l & 15;
    const int lk = l >> 4;

    const u16* arow = xb + ((size_t)(wid * 16 + lr)) * 64 + lk * 8;
    short8 a0 = *(const short8*)arow;
    short8 a1 = *(const short8*)(arow + 32);

    float dvals[4];
#pragma unroll
    for (int rg = 0; rg < 4; ++rg) dvals[rg] = dis[wid * 16 + lk * 4 + rg];

    for (int ct = 0; ct < 8; ++ct) {
        const u16* wrow = WTin + ((size_t)(ct * 16 + lr)) * 64 + lk * 8;
        short8 b0 = *(const short8*)wrow;
        short8 b1 = *(const short8*)(wrow + 32);
        f32x4 acc = {0.f, 0.f, 0.f, 0.f};
        acc = __builtin_amdgcn_mfma_f32_16x16x32_bf16(a0, b0, acc, 0, 0, 0);
        acc = __builtin_amdgcn_mfma_f32_16x16x32_bf16(a1, b1, acc, 0, 0, 0);
        const int col = ct * 16 + lr;
        if (col < 64) {
#pragma unroll
            for (int rg = 0; rg < 4; ++rg) {
                int r = wid * 16 + lk * 4 + rg;
                hws1[(size_t)r * 64 + col] = f2bf(dvals[rg] * acc[rg]);
            }
        } else {
            float be = bego[col - 64];
#pragma unroll
            for (int rg = 0; rg < 4; ++rg) {
                int r = wid * 16 + lk * 4 + rg;
                p0[(size_t)r * 64 + (col - 64)] = f2bf(fmaxf(acc[rg] + be, 0.f));
            }
        }
    }
}

// MFMA classifier slice 0: out = bcls + p0 @ Wcls0.
__global__ __launch_bounds__(256) void k_cls0(const u16* __restrict__ p0,
                                              const u16* __restrict__ WTc0,
                                              const float* __restrict__ bcls,
                                              float* __restrict__ out, int N) {
    const int wid = (blockIdx.x * 256 + threadIdx.x) >> 6;
    const int l = threadIdx.x & 63;
    if (wid * 16 >= N) return;
    const int lr = l & 15;
    const int lk = l >> 4;

    const u16* arow = p0 + ((size_t)(wid * 16 + lr)) * 64 + lk * 8;
    short8 a0 = *(const short8*)arow;
    short8 a1 = *(const short8*)(arow + 32);

    for (int ct = 0; ct < 3; ++ct) {
        const u16* wrow = WTc0 + ((size_t)(ct * 16 + lr)) * 64 + lk * 8;
        short8 b0 = *(const short8*)wrow;
        short8 b1 = *(const short8*)(wrow + 32);
        f32x4 acc = {0.f, 0.f, 0.f, 0.f};
        acc = __builtin_amdgcn_mfma_f32_16x16x32_bf16(a0, b0, acc, 0, 0, 0);
        acc = __builtin_amdgcn_mfma_f32_16x16x32_bf16(a1, b1, acc, 0, 0, 0);
        const int col = ct * 16 + lr;
        if (col < 40) {
            float bc = bcls[col];
#pragma unroll
            for (int rg = 0; rg < 4; ++rg) {
                int r = wid * 16 + lk * 4 + rg;
                out[(size_t)r * 40 + col] = bc + acc[rg];
            }
        }
    }
}

// ===========================================================================
// Pure gather: one wave per node, lane f = feature (bf16, fp32 accumulate).
__global__ __launch_bounds__(512) void k_gather(const int* __restrict__ indptr,
                                                const int* __restrict__ rows,
                                                const float* __restrict__ dis,
                                                const float* __restrict__ bconv,
                                                const u16* __restrict__ hws_in,
                                                u16* __restrict__ h, int N) {
    const int w = threadIdx.x >> 6;
    const int f = threadIdx.x & 63;
    const int i = blockIdx.x * 8 + w;
    if (i >= N) return;

    float acc = bf2f(hws_in[(size_t)i * 64 + f]);   // self-loop term
    int p0 = __builtin_amdgcn_readfirstlane(indptr[i]);
    int p1 = __builtin_amdgcn_readfirstlane(indptr[i + 1]);
    int p = p0;
    for (; p + 8 <= p1; p += 8) {
        int r0 = rows[p + 0], r1 = rows[p + 1], r2 = rows[p + 2], r3 = rows[p + 3];
        int r4 = rows[p + 4], r5 = rows[p + 5], r6 = rows[p + 6], r7 = rows[p + 7];
        u16 v0 = hws_in[(size_t)r0 * 64 + f];
        u16 v1 = hws_in[(size_t)r1 * 64 + f];
        u16 v2 = hws_in[(size_t)r2 * 64 + f];
        u16 v3 = hws_in[(size_t)r3 * 64 + f];
        u16 v4 = hws_in[(size_t)r4 * 64 + f];
        u16 v5 = hws_in[(size_t)r5 * 64 + f];
        u16 v6 = hws_in[(size_t)r6 * 64 + f];
        u16 v7 = hws_in[(size_t)r7 * 64 + f];
        acc += ((bf2f(v0) + bf2f(v1)) + (bf2f(v2) + bf2f(v3))) +
               ((bf2f(v4) + bf2f(v5)) + (bf2f(v6) + bf2f(v7)));
    }
    for (; p + 4 <= p1; p += 4) {
        int r0 = rows[p + 0], r1 = rows[p + 1], r2 = rows[p + 2], r3 = rows[p + 3];
        u16 v0 = hws_in[(size_t)r0 * 64 + f];
        u16 v1 = hws_in[(size_t)r1 * 64 + f];
        u16 v2 = hws_in[(size_t)r2 * 64 + f];
        u16 v3 = hws_in[(size_t)r3 * 64 + f];
        acc += (bf2f(v0) + bf2f(v1)) + (bf2f(v2) + bf2f(v3));
    }
    for (; p < p1; ++p) acc += bf2f(hws_in[(size_t)rows[p] * 64 + f]);

    float hv = fmaxf(fmaf(dis[i], acc, bconv[f]), 0.0f);
    h[(size_t)i * 64 + f] = f2bf(hv);
}

// MFMA MLP: D[N,*] = h[N,64] @ WT^T; epilogue per template (see R6).
template <int NC, bool HAS_NEXT>
__global__ __launch_bounds__(256) void k_mlp(const u16* __restrict__ h,
                                             const u16* __restrict__ WT,
                                             const float* __restrict__ dis,
                                             u16* __restrict__ hws_out,
                                             float* __restrict__ out, int N) {
    const int wid = (blockIdx.x * 256 + threadIdx.x) >> 6;
    const int l = threadIdx.x & 63;
    if (wid * 16 >= N) return;
    const int lr = l & 15;
    const int lk = l >> 4;

    const u16* hrow = h + ((size_t)(wid * 16 + lr)) * 64 + lk * 8;
    short8 a0 = *(const short8*)hrow;
    short8 a1 = *(const short8*)(hrow + 32);

    float dvals[4];
    if (HAS_NEXT) {
#pragma unroll
        for (int rg = 0; rg < 4; ++rg) dvals[rg] = dis[wid * 16 + lk * 4 + rg];
    }

    for (int ct = 0; ct < NC; ++ct) {
        const u16* wrow = WT + ((size_t)(ct * 16 + lr)) * 64 + lk * 8;
        short8 b0 = *(const short8*)wrow;
        short8 b1 = *(const short8*)(wrow + 32);
        f32x4 acc = {0.f, 0.f, 0.f, 0.f};
        acc = __builtin_amdgcn_mfma_f32_16x16x32_bf16(a0, b0, acc, 0, 0, 0);
        acc = __builtin_amdgcn_mfma_f32_16x16x32_bf16(a1, b1, acc, 0, 0, 0);
        const int col = ct * 16 + lr;
#pragma unroll
        for (int rg = 0; rg < 4; ++rg) {
            const int r = wid * 16 + lk * 4 + rg;
            if (HAS_NEXT) {
                if (col < 64) {
                    hws_out[(size_t)r * 64 + col] = f2bf(dvals[rg] * acc[rg]);
                } else {
                    int oc = col - 64;
                    if (oc < 40) out[(size_t)r * 40 + oc] += acc[rg];
                }
            } else {
                if (col < 40) out[(size_t)r * 40 + col] += acc[rg];
            }
        }
    }
}

// ===========================================================================
extern "C" void kernel_launch(void* const* d_in, const int* in_sizes, int n_in,
                              void* d_out, int out_size, void* d_ws, size_t ws_size,
                              hipStream_t stream) {
    const float* x     = (const float*)d_in[0];
    const int*   ei    = (const int*)d_in[1];   // [2,E] int32
    const float* Wego  = (const float*)d_in[2];
    const float* bego  = (const float*)d_in[3];
    const float* Wconv = (const float*)d_in[4]; // [2,64,64]
    const float* bconv = (const float*)d_in[5]; // [2,64]
    const float* Wcls  = (const float*)d_in[6]; // [192,40]
    const float* bcls  = (const float*)d_in[7];
    float* out = (float*)d_out;

    const int N = in_sizes[0] / 64;
    const int E = in_sizes[1] / 2;
    const int NB = cdiv(N, 1 << BKT_SH);        // buckets (N=100k -> 98)

    // workspace layout:
    //  [xb u16[N*64]  (aliased: sta u64[E] used earlier, dead before k_cast)]
    //  hws1 u16[N*64] | hws2 u16[N*64] | hp u16[N*64] (p0, then h) |
    //  WTin u16[128*64] | WTc0 u16[48*64] | WT1 u16[112*64] | WT2 u16[48*64] |
    //  dis f[N] | indptr i[N+1024 pad] | bcntg i[128] | bbase i[132] |
    //  bcursor i[128] | rows i[E]
    u16* xb   = (u16*)d_ws;
    u64* sta  = (u64*)d_ws;                      // alias, dead before xb written
    u16* hws1 = xb + (size_t)N * 64;
    u16* hws2 = hws1 + (size_t)N * 64;
    u16* hp   = hws2 + (size_t)N * 64;
    u16* WTin = hp + (size_t)N * 64;
    u16* WTc0 = WTin + 128 * 64;
    u16* WT1  = WTc0 + 48 * 64;
    u16* WT2  = WT1 + 112 * 64;
    float* dis = (float*)(WT2 + 48 * 64);
    int* indptr  = (int*)(dis + N);
    int* bcntg   = indptr + N + 1024;
    int* bbase   = bcntg + 128;
    int* bcursor = bbase + 132;
    int* rows    = bcursor + 128;

    hipMemsetAsync(bcntg, 0, 128 * sizeof(int), stream);

    // ---- CSR build (2-level counting sort; also produces indptr + dis) ----
    k_bhist<<<cdiv(E, CHUNK), 256, 0, stream>>>(ei, bcntg, E);
    k_bscan<<<1, 128, 0, stream>>>(bcntg, bbase, bcursor, NB);
    k_passA<<<cdiv(E, CHUNK), 256, 0, stream>>>(ei, bcursor, sta, E);
    k_passB<<<NB, 256, 0, stream>>>(sta, bbase, indptr, dis, rows, N, NB);

    // ---- input layer (MFMA) ----
    k_cast<<<cdiv((long long)N * 8, 256), 256, 0, stream>>>(x, (u32*)xb, (long long)N * 8);
    k_prep<<<cdiv(336 * 64, 256), 256, 0, stream>>>(Wego, Wconv, Wcls, WTin, WTc0, WT1, WT2);
    k_in<<<cdiv(cdiv(N, 16), 4), 256, 0, stream>>>(xb, WTin, dis, bego, hws1, hp, N);
    k_cls0<<<cdiv(cdiv(N, 16), 4), 256, 0, stream>>>(hp, WTc0, bcls, out, N);

    const int n_rt = cdiv(N, 16);
    // ---- hop 1 ----
    k_gather<<<cdiv(N, 8), 512, 0, stream>>>(indptr, rows, dis, bconv, hws1, hp, N);
    k_mlp<7, true><<<cdiv(n_rt, 4), 256, 0, stream>>>(hp, WT1, dis, hws2, out, N);
    // ---- hop 2 ----
    k_gather<<<cdiv(N, 8), 512, 0, stream>>>(indptr, rows, dis, bconv + 64, hws2, hp, N);
    k_mlp<3, false><<<cdiv(n_rt, 4), 256, 0, stream>>>(hp, WT2, dis, nullptr, out, N);
}

// Round 8
// 215.310 us; speedup vs baseline: 2.1090x; 1.0373x over previous
//
#include <hip/hip_runtime.h>

using u16 = unsigned short;
using u32 = unsigned int;
using short8 = __attribute__((ext_vector_type(8))) short;
using f32x4  = __attribute__((ext_vector_type(4))) float;

static inline int cdiv(long long a, long long b) { return (int)((a + b - 1) / b); }

__device__ __forceinline__ u16 f2bf(float x) {
    u32 u = __builtin_bit_cast(u32, x);
    u += 0x7fffu + ((u >> 16) & 1u);   // RTNE
    return (u16)(u >> 16);
}
__device__ __forceinline__ float bf2f(u16 h) {
    u32 u = ((u32)h) << 16;
    return __builtin_bit_cast(float, u);
}

// ===========================================================================
// CSR build, 2-level counting sort. Bucket = 1024 destination nodes.
// Staging word: (c & 1023) << 17 | r   -- requires N < 131072.
#define BKT_SH 10
#define BKT_MASK ((1 << BKT_SH) - 1)
#define CHUNK 4096

__global__ __launch_bounds__(256) void k_bhist(const int* __restrict__ ei,
                                               int* __restrict__ bcntg, int E) {
    __shared__ int lb[128];
    if (threadIdx.x < 128) lb[threadIdx.x] = 0;
    __syncthreads();
    const int eb = blockIdx.x * CHUNK;
#pragma unroll
    for (int k = 0; k < 16; ++k) {
        int e = eb + k * 256 + threadIdx.x;
        if (e < E) atomicAdd(&lb[ei[E + e] >> BKT_SH], 1);
    }
    __syncthreads();
    if (threadIdx.x < 128 && lb[threadIdx.x] > 0)
        atomicAdd(&bcntg[threadIdx.x], lb[threadIdx.x]);
}

__global__ __launch_bounds__(128) void k_bscan(const int* __restrict__ bcntg,
                                               int* __restrict__ bbase,
                                               int* __restrict__ bcursor, int NB) {
    __shared__ int s[128];
    int t = threadIdx.x;
    int v = (t < NB) ? bcntg[t] : 0;
    s[t] = v;
    __syncthreads();
    for (int st = 1; st < 128; st <<= 1) {
        int add = (t >= st) ? s[t - st] : 0;
        __syncthreads();
        s[t] += add;
        __syncthreads();
    }
    int excl = s[t] - v;
    if (t < NB) { bbase[t] = excl; bcursor[t] = excl; }
    if (t == NB - 1) bbase[NB] = excl + v;   // == E
}

__global__ __launch_bounds__(256) void k_passA(const int* __restrict__ ei,
                                               int* __restrict__ bcursor,
                                               u32* __restrict__ sta, int E) {
    __shared__ int lcnt[128];
    __shared__ int lcur[128];
    if (threadIdx.x < 128) lcnt[threadIdx.x] = 0;
    __syncthreads();
    const int eb = blockIdx.x * CHUNK;
    int er[16], ec[16];
#pragma unroll
    for (int k = 0; k < 16; ++k) {
        int e = eb + k * 256 + threadIdx.x;
        if (e < E) {
            er[k] = ei[e];
            ec[k] = ei[E + e];
            atomicAdd(&lcnt[ec[k] >> BKT_SH], 1);
        } else {
            ec[k] = -1;
        }
    }
    __syncthreads();
    if (threadIdx.x < 128)
        lcur[threadIdx.x] = lcnt[threadIdx.x] > 0
                          ? atomicAdd(&bcursor[threadIdx.x], lcnt[threadIdx.x]) : 0;
    __syncthreads();
#pragma unroll
    for (int k = 0; k < 16; ++k) {
        if (ec[k] >= 0) {
            int pos = atomicAdd(&lcur[ec[k] >> BKT_SH], 1);
            sta[pos] = ((u32)(ec[k] & BKT_MASK) << 17) | (u32)er[k];
        }
    }
}

__global__ __launch_bounds__(256) void k_passB(const u32* __restrict__ sta,
                                               const int* __restrict__ bbase,
                                               int* __restrict__ indptr,
                                               float* __restrict__ dis,
                                               int* __restrict__ rows,
                                               int N, int NB) {
    __shared__ int lcnt[1024];
    __shared__ int cur[1024];
    __shared__ int ps[256];
    const int b = blockIdx.x;
    const int t = threadIdx.x;
    const int base = b << BKT_SH;
    const int e0 = bbase[b], e1 = bbase[b + 1];

#pragma unroll
    for (int k = 0; k < 4; ++k) lcnt[k * 256 + t] = 0;
    __syncthreads();
    for (int e = e0 + t; e < e1; e += 256)
        atomicAdd(&lcnt[sta[e] >> 17], 1);
    __syncthreads();

    int a0 = lcnt[t * 4 + 0], a1 = lcnt[t * 4 + 1];
    int a2 = lcnt[t * 4 + 2], a3 = lcnt[t * 4 + 3];
    int sum = a0 + a1 + a2 + a3;
    ps[t] = sum;
    __syncthreads();
    for (int st = 1; st < 256; st <<= 1) {
        int add = (t >= st) ? ps[t - st] : 0;
        __syncthreads();
        ps[t] += add;
        __syncthreads();
    }
    int ex = e0 + ps[t] - sum;
    int exs[4] = {ex, ex + a0, ex + a0 + a1, ex + a0 + a1 + a2};
    int cnts[4] = {a0, a1, a2, a3};
#pragma unroll
    for (int k = 0; k < 4; ++k) {
        int j = t * 4 + k;
        cur[j] = exs[k];
        int node = base + j;
        if (node < N) {
            indptr[node] = exs[k];
            dis[node] = rsqrtf((float)cnts[k] + 1.0f);   // self-loop adds 1
        }
    }
    if (b == NB - 1 && t == 0) indptr[N] = bbase[NB];    // == E
    __syncthreads();

    for (int e = e0 + t; e < e1; e += 256) {
        u32 v = sta[e];
        int pos = atomicAdd(&cur[v >> 17], 1);
        rows[pos] = (int)(v & 0x1FFFF);
    }
}

// ===========================================================================
// Transposed bf16 weight panels.
// WTin  [128][64]: rows 0..63 = Wconv[0] cols; 64..127 = Wego cols.
// WT1   [64][64] : Wconv[1]^T.
// WcatT [48][192]: WcatT[c][d] = Wcls[d][c]  (c<40; pad 0).
__global__ __launch_bounds__(256) void k_prep(const float* __restrict__ Wego,
                                              const float* __restrict__ Wconv,
                                              const float* __restrict__ Wcls,
                                              u16* __restrict__ WTin,
                                              u16* __restrict__ WT1,
                                              u16* __restrict__ WcatT) {
    int t = blockIdx.x * 256 + threadIdx.x;
    if (t < 128 * 64) {
        int seg = t >> 6, d = t & 63;
        float v = (seg < 64) ? Wconv[d * 64 + seg] : Wego[d * 64 + (seg - 64)];
        WTin[t] = f2bf(v);
    } else if (t < 128 * 64 + 64 * 64) {
        int u = t - 128 * 64;
        int c = u >> 6, d = u & 63;
        WT1[u] = f2bf(Wconv[64 * 64 + d * 64 + c]);
    } else if (t < 128 * 64 + 64 * 64 + 48 * 192) {
        int u = t - (128 * 64 + 64 * 64);
        int c = u / 192, d = u - c * 192;
        WcatT[u] = f2bf(c < 40 ? Wcls[d * 40 + c] : 0.f);
    }
}

// ===========================================================================
// Fused cast + input layer (MFMA): reads x fp32, converts to bf16 frags.
// cols 0..63  -> hws (bf16, dis-scaled)      [= dis * x@Wconv0]
// cols 64..127-> hall[:,0:64] (relu+bego)    [= P0]
__global__ __launch_bounds__(256) void k_in(const float* __restrict__ x,
                                            const u16* __restrict__ WTin,
                                            const float* __restrict__ dis,
                                            const float* __restrict__ bego,
                                            u16* __restrict__ hws,
                                            u16* __restrict__ hall, int N) {
    const int wid = (blockIdx.x * 256 + threadIdx.x) >> 6;
    const int l = threadIdx.x & 63;
    if (wid * 16 >= N) return;
    const int lr = l & 15;
    const int lk = l >> 4;

    int r_ld = wid * 16 + lr;
    if (r_ld >= N) r_ld = N - 1;
    const float* xrow = x + (size_t)r_ld * 64 + lk * 8;
    float4 u0 = *(const float4*)(xrow);
    float4 u1 = *(const float4*)(xrow + 4);
    float4 u2 = *(const float4*)(xrow + 32);
    float4 u3 = *(const float4*)(xrow + 36);
    short8 a0, a1;
    a0[0] = (short)f2bf(u0.x); a0[1] = (short)f2bf(u0.y);
    a0[2] = (short)f2bf(u0.z); a0[3] = (short)f2bf(u0.w);
    a0[4] = (short)f2bf(u1.x); a0[5] = (short)f2bf(u1.y);
    a0[6] = (short)f2bf(u1.z); a0[7] = (short)f2bf(u1.w);
    a1[0] = (short)f2bf(u2.x); a1[1] = (short)f2bf(u2.y);
    a1[2] = (short)f2bf(u2.z); a1[3] = (short)f2bf(u2.w);
    a1[4] = (short)f2bf(u3.x); a1[5] = (short)f2bf(u3.y);
    a1[6] = (short)f2bf(u3.z); a1[7] = (short)f2bf(u3.w);

    float dvals[4];
#pragma unroll
    for (int rg = 0; rg < 4; ++rg) {
        int r = wid * 16 + lk * 4 + rg;
        dvals[rg] = dis[r < N ? r : N - 1];
    }

    for (int ct = 0; ct < 8; ++ct) {
        const u16* wrow = WTin + ((size_t)(ct * 16 + lr)) * 64 + lk * 8;
        short8 b0 = *(const short8*)wrow;
        short8 b1 = *(const short8*)(wrow + 32);
        f32x4 acc = {0.f, 0.f, 0.f, 0.f};
        acc = __builtin_amdgcn_mfma_f32_16x16x32_bf16(a0, b0, acc, 0, 0, 0);
        acc = __builtin_amdgcn_mfma_f32_16x16x32_bf16(a1, b1, acc, 0, 0, 0);
        const int col = ct * 16 + lr;
        if (col < 64) {
#pragma unroll
            for (int rg = 0; rg < 4; ++rg) {
                int r = wid * 16 + lk * 4 + rg;
                if (r < N) hws[(size_t)r * 64 + col] = f2bf(dvals[rg] * acc[rg]);
            }
        } else {
            float be = bego[col - 64];
#pragma unroll
            for (int rg = 0; rg < 4; ++rg) {
                int r = wid * 16 + lk * 4 + rg;
                if (r < N) hall[(size_t)r * 192 + (col - 64)] = f2bf(fmaxf(acc[rg] + be, 0.f));
            }
        }
    }
}

// ===========================================================================
// Pure gather: one wave per node, lane f = feature; writes h into hall slice.
__global__ __launch_bounds__(512) void k_gather(const int* __restrict__ indptr,
                                                const int* __restrict__ rows,
                                                const float* __restrict__ dis,
                                                const float* __restrict__ bconv,
                                                const u16* __restrict__ hws_in,
                                                u16* __restrict__ hdst, int N) {
    const int w = threadIdx.x >> 6;
    const int f = threadIdx.x & 63;
    const int i = blockIdx.x * 8 + w;
    if (i >= N) return;

    float acc = bf2f(hws_in[(size_t)i * 64 + f]);   // self-loop term
    int p0 = __builtin_amdgcn_readfirstlane(indptr[i]);
    int p1 = __builtin_amdgcn_readfirstlane(indptr[i + 1]);
    int p = p0;
    for (; p + 8 <= p1; p += 8) {
        int r0 = rows[p + 0], r1 = rows[p + 1], r2 = rows[p + 2], r3 = rows[p + 3];
        int r4 = rows[p + 4], r5 = rows[p + 5], r6 = rows[p + 6], r7 = rows[p + 7];
        u16 v0 = hws_in[(size_t)r0 * 64 + f];
        u16 v1 = hws_in[(size_t)r1 * 64 + f];
        u16 v2 = hws_in[(size_t)r2 * 64 + f];
        u16 v3 = hws_in[(size_t)r3 * 64 + f];
        u16 v4 = hws_in[(size_t)r4 * 64 + f];
        u16 v5 = hws_in[(size_t)r5 * 64 + f];
        u16 v6 = hws_in[(size_t)r6 * 64 + f];
        u16 v7 = hws_in[(size_t)r7 * 64 + f];
        acc += ((bf2f(v0) + bf2f(v1)) + (bf2f(v2) + bf2f(v3))) +
               ((bf2f(v4) + bf2f(v5)) + (bf2f(v6) + bf2f(v7)));
    }
    for (; p + 4 <= p1; p += 4) {
        int r0 = rows[p + 0], r1 = rows[p + 1], r2 = rows[p + 2], r3 = rows[p + 3];
        u16 v0 = hws_in[(size_t)r0 * 64 + f];
        u16 v1 = hws_in[(size_t)r1 * 64 + f];
        u16 v2 = hws_in[(size_t)r2 * 64 + f];
        u16 v3 = hws_in[(size_t)r3 * 64 + f];
        acc += (bf2f(v0) + bf2f(v1)) + (bf2f(v2) + bf2f(v3));
    }
    for (; p < p1; ++p) acc += bf2f(hws_in[(size_t)rows[p] * 64 + f]);

    float hv = fmaxf(fmaf(dis[i], acc, bconv[f]), 0.0f);
    hdst[(size_t)i * 192 + f] = f2bf(hv);
}

// ===========================================================================
// hws2 = bf16(dis * (h1 @ Wconv1)), h1 = hall[:,64:128].
__global__ __launch_bounds__(256) void k_next1(const u16* __restrict__ hall,
                                               const u16* __restrict__ WT1,
                                               const float* __restrict__ dis,
                                               u16* __restrict__ hws, int N) {
    const int wid = (blockIdx.x * 256 + threadIdx.x) >> 6;
    const int l = threadIdx.x & 63;
    if (wid * 16 >= N) return;
    const int lr = l & 15;
    const int lk = l >> 4;

    int r_ld = wid * 16 + lr;
    if (r_ld >= N) r_ld = N - 1;
    const u16* arow = hall + (size_t)r_ld * 192 + 64 + lk * 8;
    short8 a0 = *(const short8*)arow;
    short8 a1 = *(const short8*)(arow + 32);

    float dvals[4];
#pragma unroll
    for (int rg = 0; rg < 4; ++rg) {
        int r = wid * 16 + lk * 4 + rg;
        dvals[rg] = dis[r < N ? r : N - 1];
    }

    for (int ct = 0; ct < 4; ++ct) {
        const u16* wrow = WT1 + ((size_t)(ct * 16 + lr)) * 64 + lk * 8;
        short8 b0 = *(const short8*)wrow;
        short8 b1 = *(const short8*)(wrow + 32);
        f32x4 acc = {0.f, 0.f, 0.f, 0.f};
        acc = __builtin_amdgcn_mfma_f32_16x16x32_bf16(a0, b0, acc, 0, 0, 0);
        acc = __builtin_amdgcn_mfma_f32_16x16x32_bf16(a1, b1, acc, 0, 0, 0);
        const int col = ct * 16 + lr;
#pragma unroll
        for (int rg = 0; rg < 4; ++rg) {
            int r = wid * 16 + lk * 4 + rg;
            if (r < N) hws[(size_t)r * 64 + col] = f2bf(dvals[rg] * acc[rg]);
        }
    }
}

// ===========================================================================
// Final classifier: out = bcls + hall[N,192] @ Wcls[192,40]. Single write.
__global__ __launch_bounds__(256) void k_clsall(const u16* __restrict__ hall,
                                                const u16* __restrict__ WcatT,
                                                const float* __restrict__ bcls,
                                                float* __restrict__ out, int N) {
    const int wid = (blockIdx.x * 256 + threadIdx.x) >> 6;
    const int l = threadIdx.x & 63;
    if (wid * 16 >= N) return;
    const int lr = l & 15;
    const int lk = l >> 4;

    int r_ld = wid * 16 + lr;
    if (r_ld >= N) r_ld = N - 1;
    const u16* arow = hall + (size_t)r_ld * 192 + lk * 8;
    short8 a[6];
#pragma unroll
    for (int kt = 0; kt < 6; ++kt) a[kt] = *(const short8*)(arow + kt * 32);

    for (int ct = 0; ct < 3; ++ct) {
        const u16* brow = WcatT + ((size_t)(ct * 16 + lr)) * 192 + lk * 8;
        f32x4 acc = {0.f, 0.f, 0.f, 0.f};
#pragma unroll
        for (int kt = 0; kt < 6; ++kt) {
            short8 b = *(const short8*)(brow + kt * 32);
            acc = __builtin_amdgcn_mfma_f32_16x16x32_bf16(a[kt], b, acc, 0, 0, 0);
        }
        const int col = ct * 16 + lr;
        if (col < 40) {
            float bc = bcls[col];
#pragma unroll
            for (int rg = 0; rg < 4; ++rg) {
                int r = wid * 16 + lk * 4 + rg;
                if (r < N) out[(size_t)r * 40 + col] = bc + acc[rg];
            }
        }
    }
}

// ===========================================================================
extern "C" void kernel_launch(void* const* d_in, const int* in_sizes, int n_in,
                              void* d_out, int out_size, void* d_ws, size_t ws_size,
                              hipStream_t stream) {
    const float* x     = (const float*)d_in[0];
    const int*   ei    = (const int*)d_in[1];   // [2,E] int32
    const float* Wego  = (const float*)d_in[2];
    const float* bego  = (const float*)d_in[3];
    const float* Wconv = (const float*)d_in[4]; // [2,64,64]
    const float* bconv = (const float*)d_in[5]; // [2,64]
    const float* Wcls  = (const float*)d_in[6]; // [192,40]
    const float* bcls  = (const float*)d_in[7];
    float* out = (float*)d_out;

    const int N = in_sizes[0] / 64;
    const int E = in_sizes[1] / 2;
    const int NB = cdiv(N, 1 << BKT_SH);

    // workspace layout (u16 units unless noted):
    //  hall u16[N*192]  (aliased early: sta u32[E], dead before k_in)
    //  hwsbuf u16[N*64] (hws1, later overwritten by hws2)
    //  WTin[128*64] | WT1[64*64] | WcatT[48*192] |
    //  dis f[N] | indptr i[N+1+pad] | bcntg i[128] | bbase i[132] |
    //  bcursor i[128] | rows i[E]
    u16* hall   = (u16*)d_ws;
    u32* sta    = (u32*)d_ws;                    // alias, dead before k_in
    u16* hwsbuf = hall + (size_t)N * 192;
    u16* WTin   = hwsbuf + (size_t)N * 64;
    u16* WT1    = WTin + 128 * 64;
    u16* WcatT  = WT1 + 64 * 64;
    float* dis  = (float*)(WcatT + 48 * 192);
    int* indptr  = (int*)(dis + N);
    int* bcntg   = indptr + N + 64;
    int* bbase   = bcntg + 128;
    int* bcursor = bbase + 132;
    int* rows    = bcursor + 128;

    hipMemsetAsync(bcntg, 0, 128 * sizeof(int), stream);

    // ---- CSR build (2-level counting sort; produces indptr + dis + rows) ----
    k_bhist<<<cdiv(E, CHUNK), 256, 0, stream>>>(ei, bcntg, E);
    k_bscan<<<1, 128, 0, stream>>>(bcntg, bbase, bcursor, NB);
    k_passA<<<cdiv(E, CHUNK), 256, 0, stream>>>(ei, bcursor, sta, E);
    k_passB<<<NB, 256, 0, stream>>>(sta, bbase, indptr, dis, rows, N, NB);

    // ---- weights + input layer (fused cast, MFMA) ----
    k_prep<<<cdiv(128 * 64 + 64 * 64 + 48 * 192, 256), 256, 0, stream>>>(
        Wego, Wconv, Wcls, WTin, WT1, WcatT);
    const int n_blk16 = cdiv(cdiv(N, 16), 4);
    k_in<<<n_blk16, 256, 0, stream>>>(x, WTin, dis, bego, hwsbuf, hall, N);

    // ---- hop 1: gather hws1 -> h1 (hall slice 1); hws2 = dis*(h1@Wconv1) ----
    k_gather<<<cdiv(N, 8), 512, 0, stream>>>(indptr, rows, dis, bconv,
                                             hwsbuf, hall + 64, N);
    k_next1<<<n_blk16, 256, 0, stream>>>(hall, WT1, dis, hwsbuf, N);

    // ---- hop 2: gather hws2 -> h2 (hall slice 2) ----
    k_gather<<<cdiv(N, 8), 512, 0, stream>>>(indptr, rows, dis, bconv + 64,
                                             hwsbuf, hall + 128, N);

    // ---- classifier: out = bcls + hall @ Wcls (single pass) ----
    k_clsall<<<n_blk16, 256, 0, stream>>>(hall, WcatT, bcls, out, N);
}